// Round 12
// baseline (142.260 us; speedup 1.0000x reference)
//
#include <hip/hip_runtime.h>

// RecursiveNN: 11-level binary tree, shared linear map W(128x256)+b, bf16 MFMA.
// Evidence ledger (r0-r11):
//   - Harness re-poisons 256MB ws EVERY iteration (fillBufferAligned 41.5us,
//     fixed) -> etab bf16 table must be rebuilt per-iteration (13us) and L3 is
//     flushed (explains invariant 2.3-2.4x table-size HBM re-fetch).
//   - etab never paid net: gather -11us vs prep +13us (r7/r8/r11 totals).
//   - Quad algebra (W2=[WlWl|WlWr|WrWl|WrWr], b2=(Wl+Wr)b+b) VERIFIED
//     (r9/r10/r11 passed, absmax 0.0024); quad ladder = -4us in tree128 (r11)
//     but its r9-style infrastructure (W2-on-prep-critical-path, 192-reg
//     tree32) cost +13.5us. This round keeps the -4, drops the +13.5:
//     * no etab: fp32 reg-staged gather (r6/r11-fallback proven pattern)
//     * prep = 49 blocks only (W1 pack, W2 compute, b2): ~2-3us
//     * tree32 = r8's light W1-only version (64 regs, proven)
//   - STRIDE=136 padded LDS + stride-2-row reads: 0 conflicts across 10
//     rounds. Unpadded XOR attempts failed twice (r9/r10) - banned.
//   - r10 spill lesson: 128 resident W2 regs need (256,2) budget.
// Tripwires: WRITE_SIZE >> 2MB = spill; conflicts > 0.5M = layout regression.
// If tree128 >= 48us with both clean -> random-gather ceiling governs ->
// structural floor reached.

typedef __bf16 bf16x8 __attribute__((ext_vector_type(8)));
typedef __bf16 bf16x4 __attribute__((ext_vector_type(4)));
typedef float f32x4 __attribute__((ext_vector_type(4)));

#define STRIDE 136  // 128 cols + 8 pad bf16 = 272B rows; 0 LDS conflicts measured

// Raw barrier: orders LDS ops without draining vmcnt.
#define BARRIER() do {                                          \
    asm volatile("s_waitcnt lgkmcnt(0)" ::: "memory");          \
    __builtin_amdgcn_s_barrier();                               \
} while (0)

// prep (49 blocks): blocks 0-15 pack W1 -> wpack1 (frag f: o=(2wv+nl)*16+
// (l&15), d=kk*32+(l>>4)*8, elem j = W[o][d+j]); blocks 16-47 compute+pack W2
// (f2=nl*16+kk, quadrant s=d>>7: W2[o][d] = sum_k W[o,(s>>1)*128+k] *
// W[k,(s&1)*128+(d&127)]); block 48: b2 = (Wl+Wr)b + b. No etab.
__global__ void prep_kernel(const float* __restrict__ W,
                            const float* __restrict__ bias,
                            __bf16* __restrict__ wpack1,
                            __bf16* __restrict__ wpack2,
                            float* __restrict__ b2) {
    const int tid = threadIdx.x;
    const int bx = blockIdx.x;
    const int wv = tid >> 6, l = tid & 63;
    if (bx < 16) {
        const int nl = bx >> 3, kk = bx & 7;
        const int o = ((wv << 1) + nl) * 16 + (l & 15);
        const int d = kk * 32 + ((l >> 4) << 3);
        const float* src = W + o * 256 + d;
        bf16x8 h;
#pragma unroll
        for (int j = 0; j < 8; ++j) h[j] = (__bf16)src[j];
        *(bf16x8*)(wpack1 + (size_t)(bx * 256 + tid) * 8) = h;
    } else if (bx < 48) {
        const int f2 = bx - 16;                  // 0..31
        const int nl = f2 >> 4, kk = f2 & 15;
        const int o = ((wv << 1) + nl) * 16 + (l & 15);
        const int d = kk * 32 + ((l >> 4) << 3); // 0..511, 8-elem block
        const int s = d >> 7, c = d & 127;       // quadrant, inner col
        const float* wrow = W + o * 256 + (s >> 1) * 128;
        const float* wcol = W + (s & 1) * 128 + c;
        float a8[8] = {0, 0, 0, 0, 0, 0, 0, 0};
        for (int k = 0; k < 128; ++k) {
            const float wl = wrow[k];
            const float* wr = wcol + k * 256;
#pragma unroll
            for (int j = 0; j < 8; ++j) a8[j] += wl * wr[j];
        }
        bf16x8 h;
#pragma unroll
        for (int j = 0; j < 8; ++j) h[j] = (__bf16)a8[j];
        *(bf16x8*)(wpack2 + (size_t)(f2 * 256 + tid) * 8) = h;
    } else {
        if (tid < 128) {
            float acc = bias[tid];
            const float* wr = W + tid * 256;
            for (int k = 0; k < 128; ++k)
                acc += (wr[k] + wr[128 + k]) * bias[k];
            b2[tid] = acc;
        }
    }
}

// Quad-level accumulate on PADDED layout. Child s of node me lives at row
// 2*me + (s&1) + 32*(s>>1): reads bit-identical to r6's step32 rows
// (2lm+kh in [0,32) and +32) - measured 0 conflicts. Cols (kk&3)*32 + q*8.
template <int NOUT>
__device__ __forceinline__ void quad_acc(
    const __bf16* src, const bf16x8 (&wa)[16], const bf16x8 (&wb)[16],
    const float* b2v, int q, int lm, f32x4 (&a2)[2])
{
    const int me = (NOUT >= 16) ? lm : (lm < NOUT ? lm : 0);
    a2[0] = f32x4{ b2v[0], b2v[0], b2v[0], b2v[0] };
    a2[1] = f32x4{ b2v[1], b2v[1], b2v[1], b2v[1] };
#pragma unroll
    for (int kk = 0; kk < 16; ++kk) {
        const int s = kk >> 2;
        const int row = 2 * me + (s & 1) + 32 * (s >> 1);
        const bf16x8 af = *(const bf16x8*)
            &src[row * STRIDE + (kk & 3) * 32 + q * 8];
        a2[0] = __builtin_amdgcn_mfma_f32_16x16x32_bf16(
            af, wa[kk], a2[0], 0, 0, 0);
        a2[1] = __builtin_amdgcn_mfma_f32_16x16x32_bf16(
            af, wb[kk], a2[1], 0, 0, 0);
    }
}

// Kernel 1: one block = 256 leaves (2048 blocks). Quad ladder, 6 compute
// phases: 4x L12 (64 leaves -> 16 nodes into D), L34 (D -> E rows
// {0..7,32..39} of bufA), L56 (E -> 4 roots -> y).
// fp32 reg-staged gather (r6-proven): 32 lanes x 16B per 512B row; leaf
// perm row = 2*(l>>2)+(l&1)+32*((l>>1)&1) folded into the id lookup.
__global__ __launch_bounds__(256, 2) void tree128_kernel(
    const int* __restrict__ wid, const float* __restrict__ emb,
    const __bf16* __restrict__ wpack2, const float* __restrict__ b2,
    __bf16* __restrict__ yout)
{
    __shared__ __align__(16) __bf16 bufA[64 * STRIDE];  // 17408 B
    __shared__ __align__(16) __bf16 bufB[64 * STRIDE];  // 17408 B
    __shared__ __align__(16) __bf16 bufD[64 * STRIDE];  // 17408 B -> 52224 total
    const int tid = threadIdx.x;
    const int batch = blockIdx.x >> 3;   // 8 blocks (256 leaves) per batch
    const int pair = blockIdx.x & 7;
    const int wv = tid >> 6, ln = tid & 63, q = ln >> 4, lm = ln & 15;

    // Both W2 halves resident as two 16-frag arrays (proven wf[16] pattern x2).
    const bf16x8* wp2 = (const bf16x8*)wpack2;
    bf16x8 w2a[16], w2b[16];
#pragma unroll
    for (int f = 0; f < 16; ++f) w2a[f] = wp2[f * 256 + tid];
#pragma unroll
    for (int f = 0; f < 16; ++f) w2b[f] = wp2[(16 + f) * 256 + tid];
    float b2v[2];
    b2v[0] = b2[(2 * wv + 0) * 16 + lm];
    b2v[1] = b2[(2 * wv + 1) * 16 + lm];

    const int* wb = wid + batch * 2048 + pair * 256;

    // L12: quad level on gathered chunk c -> D.
    // Output node n = 4q+r; next-level parent m = 4c+q, child s2 = r ->
    // D row = 8c+2q+(r&1)+32*(r>>1).
    auto L12 = [&](const __bf16* src, int c) {
        f32x4 a2[2];
        quad_acc<16>(src, w2a, w2b, b2v, q, lm, a2);
#pragma unroll
        for (int nl = 0; nl < 2; ++nl) {
            const int col = (2 * wv + nl) * 16 + lm;
            const bf16x4 hv = __builtin_convertvector(a2[nl], bf16x4);
#pragma unroll
            for (int r = 0; r < 4; ++r) {
                const int row = 8 * c + 2 * q + (r & 1) + 32 * (r >> 1);
                bufD[row * STRIDE + col] = hv[r];
            }
        }
    };

    // fp32 reg-staged gather. Row -> leaf inversion:
    //   m=(row&31)>>1, s=(row&1)+2*(row>>5), leaf = 4m+s.
    f32x4 st[8];
    auto GISS = [&](int g) {
#pragma unroll
        for (int i = 0; i < 8; ++i) {
            const int row = (tid >> 5) + 8 * i;
            const int leaf =
                4 * ((row & 31) >> 1) + (row & 1) + 2 * (row >> 5);
            const int id = wb[g * 64 + leaf];
            st[i] = *(const f32x4*)(emb + (size_t)id * 128 + (tid & 31) * 4);
        }
    };
    auto GWR = [&](__bf16* dst) {
#pragma unroll
        for (int i = 0; i < 8; ++i) {
            const int row = (tid >> 5) + 8 * i;
            *(bf16x4*)&dst[row * STRIDE + (tid & 31) * 4] =
                __builtin_convertvector(st[i], bf16x4);
        }
    };
    GISS(0); GWR(bufA); BARRIER();
    GISS(1); L12(bufA, 0); GWR(bufB); BARRIER();
    GISS(2); L12(bufB, 1); GWR(bufA); BARRIER();
    GISS(3); L12(bufA, 2); GWR(bufB); BARRIER();
    L12(bufB, 3); BARRIER();

    // L34: D (64 rows) -> E. Output node n=4q+r; L56 parent m=q, child s=r
    // -> E row = 2q+(r&1)+32*(r>>1) in {0..7, 32..39} of bufA (A is dead).
    {
        f32x4 a2[2];
        quad_acc<16>(bufD, w2a, w2b, b2v, q, lm, a2);
#pragma unroll
        for (int nl = 0; nl < 2; ++nl) {
            const int col = (2 * wv + nl) * 16 + lm;
            const bf16x4 hv = __builtin_convertvector(a2[nl], bf16x4);
#pragma unroll
            for (int r = 0; r < 4; ++r) {
                const int row = 2 * q + (r & 1) + 32 * (r >> 1);
                bufA[row * STRIDE + col] = hv[r];
            }
        }
    }
    BARRIER();
    // L56: E (16 nodes) -> 4 roots straight to y (rows 0..3 live at q==0).
    {
        f32x4 a2[2];
        quad_acc<4>(bufA, w2a, w2b, b2v, q, lm, a2);
        __bf16* yrow = yout + (size_t)(batch * 32 + pair * 4) * 128;
#pragma unroll
        for (int nl = 0; nl < 2; ++nl) {
            const int col = (2 * wv + nl) * 16 + lm;
            if (q == 0) {
#pragma unroll
                for (int r = 0; r < 4; ++r)
                    yrow[r * 128 + col] = (__bf16)a2[nl][r];
            }
        }
    }
}

// ---- tree32: r8's light W1-only version (proven in the 128.4/130.7 configs).
// One block = one batch; 32 subtree roots -> 5 pair levels -> fp32 row.
template <int NOUT>
__device__ __forceinline__ void step_small(
    const __bf16* src, __bf16* dst,
    const bf16x8 (&wf)[16], const float* bval, int wv, int q, int lm)
{
    const int me = (NOUT >= 16) ? lm : (lm < NOUT ? lm : 0);
    f32x4 acc[2];
    acc[0] = f32x4{ bval[0], bval[0], bval[0], bval[0] };
    acc[1] = f32x4{ bval[1], bval[1], bval[1], bval[1] };
#pragma unroll
    for (int kh = 0; kh < 2; ++kh) {
        const int row = 2 * me + kh;
        bf16x8 af[4];
#pragma unroll
        for (int j = 0; j < 4; ++j)
            af[j] = *(const bf16x8*)&src[row * STRIDE + j * 32 + q * 8];
#pragma unroll
        for (int nl = 0; nl < 2; ++nl)
#pragma unroll
            for (int j = 0; j < 4; ++j)
                acc[nl] = __builtin_amdgcn_mfma_f32_16x16x32_bf16(
                    af[j], wf[nl * 8 + kh * 4 + j], acc[nl], 0, 0, 0);
    }
#pragma unroll
    for (int nl = 0; nl < 2; ++nl) {
        const int col = (2 * wv + nl) * 16 + lm;
        const bf16x4 hv = __builtin_convertvector(acc[nl], bf16x4);
#pragma unroll
        for (int r = 0; r < 4; ++r) {
            const int row = q * 4 + r;
            if (row < NOUT)
                dst[row * STRIDE + col] = hv[r];
        }
    }
}

__global__ __launch_bounds__(256) void tree32_kernel(
    const __bf16* __restrict__ yin, const __bf16* __restrict__ wpack1,
    const float* __restrict__ bias, float* __restrict__ out)
{
    __shared__ __align__(16) __bf16 buf0[32 * STRIDE];  // 8704 B
    __shared__ __align__(16) __bf16 buf1[16 * STRIDE];  // 4352 B
    const int tid = threadIdx.x;
    const int batch = blockIdx.x;
    const int wv = tid >> 6, ln = tid & 63, q = ln >> 4, lm = ln & 15;

    bf16x8 wf[16];
    const bf16x8* wp = (const bf16x8*)wpack1;
#pragma unroll
    for (int f = 0; f < 16; ++f) wf[f] = wp[f * 256 + tid];
    float bval[2];
    bval[0] = bias[(2 * wv + 0) * 16 + lm];
    bval[1] = bias[(2 * wv + 1) * 16 + lm];

#pragma unroll
    for (int i = 0; i < 2; ++i) {
        const int flat = tid + 256 * i;
        const int row = flat >> 4;
        const int c8 = flat & 15;
        const bf16x8 v =
            *(const bf16x8*)(yin + (size_t)(batch * 32 + row) * 128 + c8 * 8);
        *(bf16x8*)&buf0[row * STRIDE + c8 * 8] = v;
    }
    __syncthreads();

    step_small<16>(buf0, buf1, wf, bval, wv, q, lm);  __syncthreads();
    step_small<8> (buf1, buf0, wf, bval, wv, q, lm);  __syncthreads();
    step_small<4> (buf0, buf1, wf, bval, wv, q, lm);  __syncthreads();
    step_small<2> (buf1, buf0, wf, bval, wv, q, lm);  __syncthreads();

    // Final: rows 0,1 of buf0 -> root row (fp32 out).
    {
        f32x4 acc[2];
        acc[0] = f32x4{ bval[0], bval[0], bval[0], bval[0] };
        acc[1] = f32x4{ bval[1], bval[1], bval[1], bval[1] };
#pragma unroll
        for (int kh = 0; kh < 2; ++kh) {
            bf16x8 af[4];
#pragma unroll
            for (int j = 0; j < 4; ++j)
                af[j] = *(const bf16x8*)&buf0[kh * STRIDE + j * 32 + q * 8];
#pragma unroll
            for (int nl = 0; nl < 2; ++nl)
#pragma unroll
                for (int j = 0; j < 4; ++j)
                    acc[nl] = __builtin_amdgcn_mfma_f32_16x16x32_bf16(
                        af[j], wf[nl * 8 + kh * 4 + j], acc[nl], 0, 0, 0);
        }
#pragma unroll
        for (int nl = 0; nl < 2; ++nl) {
            const int col = (2 * wv + nl) * 16 + lm;
            if (q == 0) out[(size_t)batch * 128 + col] = acc[nl][0];
        }
    }
}

extern "C" void kernel_launch(void* const* d_in, const int* in_sizes, int n_in,
                              void* d_out, int out_size, void* d_ws, size_t ws_size,
                              hipStream_t stream) {
    const int*   wid = (const int*)d_in[0];      // (256, 2048) int32
    const float* emb = (const float*)d_in[1];    // (100000, 128) fp32
    const float* W   = (const float*)d_in[2];    // (128, 256) fp32
    const float* b   = (const float*)d_in[3];    // (128,) fp32
    float* out = (float*)d_out;                  // (256, 128) fp32

    __bf16* wpack1 = (__bf16*)d_ws;              // 32768 bf16 = 64 KB
    __bf16* wpack2 = wpack1 + 32768;             // 65536 bf16 = 128 KB
    float*  b2     = (float*)(wpack2 + 65536);   // 128 f32 = 512 B
    __bf16* y      = (__bf16*)(b2 + 128);        // (256,32,128) bf16 = 2 MB

    prep_kernel<<<49, 256, 0, stream>>>(W, b, wpack1, wpack2, b2);
    tree128_kernel<<<2048, 256, 0, stream>>>(wid, emb, wpack2, b2, y);
    tree32_kernel<<<256, 256, 0, stream>>>(y, wpack1, b, out);
}